// Round 3
// baseline (3880.973 us; speedup 1.0000x reference)
//
#include <hip/hip_runtime.h>
#include <stdint.h>

#define R_ 4096
#define L_ 32
#define C_ 512
#define H_ 4
#define DH_ 128

typedef __bf16 bf16x8 __attribute__((ext_vector_type(8)));
typedef float f32x4 __attribute__((ext_vector_type(4)));

// ---------- bf16 bit helpers (RNE) ----------
__device__ __forceinline__ float b2f(unsigned int u) {
    union { unsigned int i; float f; } x; x.i = u << 16; return x.f;
}
__device__ __forceinline__ unsigned short f2b(float f) {
    union { float f; unsigned int i; } x; x.f = f;
    unsigned int i = x.i;
    i += 0x7fffu + ((i >> 16) & 1u);
    return (unsigned short)(i >> 16);
}
__device__ __forceinline__ void unpack8(uint4 v, float* x) {
    x[0] = b2f(v.x & 0xffffu); x[1] = b2f(v.x >> 16);
    x[2] = b2f(v.y & 0xffffu); x[3] = b2f(v.y >> 16);
    x[4] = b2f(v.z & 0xffffu); x[5] = b2f(v.z >> 16);
    x[6] = b2f(v.w & 0xffffu); x[7] = b2f(v.w >> 16);
}
__device__ __forceinline__ uint4 pack8(const float* x) {
    uint4 v;
    v.x = (unsigned)f2b(x[0]) | ((unsigned)f2b(x[1]) << 16);
    v.y = (unsigned)f2b(x[2]) | ((unsigned)f2b(x[3]) << 16);
    v.z = (unsigned)f2b(x[4]) | ((unsigned)f2b(x[5]) << 16);
    v.w = (unsigned)f2b(x[6]) | ((unsigned)f2b(x[7]) << 16);
    return v;
}

// ---------- dtype detection: 1 = bf16, 0 = fp32 ----------
__global__ __launch_bounds__(256)
void detect_kernel(const unsigned short* __restrict__ gene, int* __restrict__ flag) {
    __shared__ int cnt;
    if (threadIdx.x == 0) cnt = 0;
    __syncthreads();
    int local = 0;
    for (int j = 0; j < 8; ++j) {
        int i = threadIdx.x * 8 + j;          // even 2-byte elems 0,2,...,4094
        unsigned short u = gene[2 * i];
        int e = (u >> 7) & 0xFF;
        if (e >= 100 && e <= 140) ++local;
    }
    atomicAdd(&cnt, local);
    __syncthreads();
    if (threadIdx.x == 0) *flag = (cnt >= 1024) ? 1 : 0;
}

// ---------- convert (fp32|bf16) -> bf16, branch on flag ----------
__global__ __launch_bounds__(256)
void cvt_any_kernel(const void* __restrict__ in, unsigned short* __restrict__ out,
                    int n, const int* __restrict__ flag) {
    int i0 = (blockIdx.x * 256 + threadIdx.x) * 8;
    if (i0 >= n) return;
    if (*flag) {
        *(uint4*)(out + i0) = *(const uint4*)((const unsigned short*)in + i0);
    } else {
        const float* f = (const float*)in;
        float4 a = *(const float4*)(f + i0);
        float4 b = *(const float4*)(f + i0 + 4);
        float x[8] = {a.x, a.y, a.z, a.w, b.x, b.y, b.z, b.w};
        *(uint4*)(out + i0) = pack8(x);
    }
}

// ---------- diagnostic ----------
__global__ __launch_bounds__(256)
void diag_kernel(unsigned short* __restrict__ out, int n, float val) {
    int i = blockIdx.x * 256 + threadIdx.x;
    if (i < n) out[i] = f2b(val);
}

// ---------- gather genes -> X [Mc, C] bf16, masked rows = 0 ----------
__global__ __launch_bounds__(256)
void gather_kernel(const void* __restrict__ gene_v, const int* __restrict__ gidx,
                   const int* __restrict__ lens, unsigned short* __restrict__ X,
                   const int* __restrict__ flag) {
    int tid = blockIdx.x * 256 + threadIdx.x;   // rows*64 threads, 8 elems each
    int m = tid >> 6;
    int ch = tid & 63;
    uint4 v = make_uint4(0u, 0u, 0u, 0u);
    if ((m & 31) < lens[m >> 5]) {
        size_t base = (size_t)gidx[m] * C_ + ch * 8;
        if (*flag) {
            v = *(const uint4*)((const unsigned short*)gene_v + base);
        } else {
            const float* f = (const float*)gene_v;
            float4 a = *(const float4*)(f + base);
            float4 b = *(const float4*)(f + base + 4);
            float x[8] = {a.x, a.y, a.z, a.w, b.x, b.y, b.z, b.w};
            v = pack8(x);
        }
    }
    *(uint4*)(X + (size_t)m * C_ + ch * 8) = v;
}

// ---------- seed broadcast -> Xs [Rc, C] bf16 ----------
__global__ __launch_bounds__(256)
void seed_kernel(const unsigned short* __restrict__ seed, unsigned short* __restrict__ Xs) {
    int i = blockIdx.x * 256 + threadIdx.x;  // Rc*64 threads
    int ch = i & 63;
    uint4 v = *(const uint4*)(seed + ch * 8);
    *(uint4*)(Xs + (size_t)i * 8) = v;
}

// ---------- final: S0 bf16 -> out (bf16|fp32 per flag), zero empty reactions ----------
// elem_off = r0*C_ (element offset into output)
__global__ __launch_bounds__(256)
void final_kernel(const unsigned short* __restrict__ S, const int* __restrict__ lens,
                  void* __restrict__ out, const int* __restrict__ flag, size_t elem_off) {
    int i = blockIdx.x * 256 + threadIdx.x;  // Rc*64, 8 elems each
    int r = i >> 6;
    uint4 v = make_uint4(0u, 0u, 0u, 0u);
    if (lens[r] > 0) v = *(const uint4*)(S + (size_t)i * 8);
    if (*flag) {
        *(uint4*)((unsigned short*)out + elem_off + (size_t)i * 8) = v;
    } else {
        float x[8];
        unpack8(v, x);
        float* o = (float*)out + elem_off + (size_t)i * 8;
        *(float4*)o       = make_float4(x[0], x[1], x[2], x[3]);
        *(float4*)(o + 4) = make_float4(x[4], x[5], x[6], x[7]);
    }
}

// ---------- GEMM: Out[M,512] = A[M,512] @ W[512,512]^T + bias, opt ReLU ----------
__global__ __launch_bounds__(256)
void gemm_bt_kernel(const unsigned short* __restrict__ A, const unsigned short* __restrict__ W,
                    const unsigned short* __restrict__ bias, unsigned short* __restrict__ Out,
                    int relu) {
    __shared__ unsigned short As[128][40];
    __shared__ unsigned short Bs[128][40];

    const int t = threadIdx.x;
    const int wave = t >> 6, lane = t & 63;
    const int quad = lane >> 4, lr = lane & 15;
    const int wr = wave >> 1, wc = wave & 1;
    const int m0 = blockIdx.x * 128, n0 = blockIdx.y * 128;
    const int row_s = t >> 2, chunk = t & 3;

    f32x4 acc[4][4] = {};

    for (int k0 = 0; k0 < C_; k0 += 32) {
        __syncthreads();
        {
            const uint4* ga0 = (const uint4*)(A + (size_t)(m0 + row_s) * C_ + k0);
            const uint4* ga1 = (const uint4*)(A + (size_t)(m0 + row_s + 64) * C_ + k0);
            const uint4* gb0 = (const uint4*)(W + (size_t)(n0 + row_s) * C_ + k0);
            const uint4* gb1 = (const uint4*)(W + (size_t)(n0 + row_s + 64) * C_ + k0);
            uint4 va0 = ga0[chunk], va1 = ga1[chunk], vb0 = gb0[chunk], vb1 = gb1[chunk];
            *(uint4*)&As[row_s][chunk * 8]      = va0;
            *(uint4*)&As[row_s + 64][chunk * 8] = va1;
            *(uint4*)&Bs[row_s][chunk * 8]      = vb0;
            *(uint4*)&Bs[row_s + 64][chunk * 8] = vb1;
        }
        __syncthreads();
        bf16x8 af[4], bfr[4];
#pragma unroll
        for (int i = 0; i < 4; ++i)
            af[i] = *(const bf16x8*)&As[64 * wr + 16 * i + lr][quad * 8];
#pragma unroll
        for (int j = 0; j < 4; ++j)
            bfr[j] = *(const bf16x8*)&Bs[64 * wc + 16 * j + lr][quad * 8];
#pragma unroll
        for (int i = 0; i < 4; ++i)
#pragma unroll
            for (int j = 0; j < 4; ++j)
                acc[i][j] = __builtin_amdgcn_mfma_f32_16x16x32_bf16(af[i], bfr[j], acc[i][j], 0, 0, 0);
    }

#pragma unroll
    for (int i = 0; i < 4; ++i) {
        int row = m0 + 64 * wr + 16 * i + quad * 4;
#pragma unroll
        for (int j = 0; j < 4; ++j) {
            int col = n0 + 64 * wc + 16 * j + lr;
            float bv = b2f(bias[col]);
#pragma unroll
            for (int r = 0; r < 4; ++r) {
                float v = acc[i][j][r] + bv;
                if (relu) v = fmaxf(v, 0.f);
                Out[(size_t)(row + r) * C_ + col] = f2b(v);
            }
        }
    }
}

// ---------- encoder attention: per (r,h), Lq=Lk=32, key mask ----------
__global__ __launch_bounds__(128)
void attn_enc_kernel(const unsigned short* __restrict__ Q, const unsigned short* __restrict__ K,
                     const unsigned short* __restrict__ V, unsigned short* __restrict__ O,
                     const int* __restrict__ lens) {
    const int r = blockIdx.x, h = blockIdx.y, t = threadIdx.x;
    __shared__ float Qs[32][129], Ks[32][129], Vs[32][129];
    __shared__ float Sc[32][33];
    const int len = lens[r];

    for (int it = 0; it < 4; ++it) {
        int flat = t + it * 128;            // 512 chunks of 8
        int row = flat >> 4, ch = flat & 15;
        size_t g = ((size_t)(r * 32 + row)) * C_ + h * DH_ + ch * 8;
        float xq[8], xk[8], xv[8];
        unpack8(*(const uint4*)(Q + g), xq);
        unpack8(*(const uint4*)(K + g), xk);
        unpack8(*(const uint4*)(V + g), xv);
#pragma unroll
        for (int e = 0; e < 8; ++e) {
            Qs[row][ch * 8 + e] = xq[e];
            Ks[row][ch * 8 + e] = xk[e];
            Vs[row][ch * 8 + e] = xv[e];
        }
    }
    __syncthreads();

    const int q = t >> 2, kg = t & 3;
    float accs[8] = {};
    for (int d = 0; d < 128; ++d) {
        float qv = Qs[q][d];
#pragma unroll
        for (int kk = 0; kk < 8; ++kk) accs[kk] += qv * Ks[kg * 8 + kk][d];
    }
    const float scale = 0.08838834764831845f;  // 1/sqrt(128)
#pragma unroll
    for (int kk = 0; kk < 8; ++kk) {
        int k = kg * 8 + kk;
        Sc[q][k] = (k < len) ? accs[kk] * scale : -1e30f;
    }
    __syncthreads();

    if (t < 32) {
        float mx = -3e38f;
        for (int k = 0; k < 32; ++k) mx = fmaxf(mx, Sc[t][k]);
        float sum = 0.f;
        for (int k = 0; k < 32; ++k) { float e = __expf(Sc[t][k] - mx); Sc[t][k] = e; sum += e; }
        float inv = 1.f / sum;
        for (int k = 0; k < 32; ++k) Sc[t][k] *= inv;
    }
    __syncthreads();

    const int d0 = (t & 3) * 32;
    float acc[32] = {};
    for (int k = 0; k < 32; ++k) {
        float a = Sc[q][k];
#pragma unroll
        for (int dd = 0; dd < 32; ++dd) acc[dd] += a * Vs[k][d0 + dd];
    }
    size_t g = ((size_t)(r * 32 + q)) * C_ + h * DH_ + d0;
#pragma unroll
    for (int c4 = 0; c4 < 4; ++c4) {
        float tmp[8];
#pragma unroll
        for (int e = 0; e < 8; ++e) tmp[e] = acc[c4 * 8 + e];
        *(uint4*)(O + g + c4 * 8) = pack8(tmp);
    }
}

// ---------- PMA attention: per (r,h), 1 query (seed), 32 keys, key mask ----------
__global__ __launch_bounds__(64)
void attn_pma_kernel(const unsigned short* __restrict__ Qs_, const unsigned short* __restrict__ K,
                     const unsigned short* __restrict__ V, unsigned short* __restrict__ O,
                     const int* __restrict__ lens) {
    const int r = blockIdx.x, h = blockIdx.y, t = threadIdx.x;
    __shared__ float qv[128];
    __shared__ float attn[32];
    const int len = lens[r];
    const size_t qb = (size_t)r * C_ + h * DH_;
    qv[t]      = b2f(Qs_[qb + t]);
    qv[t + 64] = b2f(Qs_[qb + t + 64]);
    __syncthreads();
    if (t < 32) {
        const unsigned short* krow = K + ((size_t)(r * 32 + t)) * C_ + h * DH_;
        float s = 0.f;
        for (int d = 0; d < 128; ++d) s += qv[d] * b2f(krow[d]);
        attn[t] = (t < len) ? s * 0.08838834764831845f : -1e30f;
    }
    __syncthreads();
    if (t == 0) {
        float mx = -3e38f;
        for (int k = 0; k < 32; ++k) mx = fmaxf(mx, attn[k]);
        float sum = 0.f;
        for (int k = 0; k < 32; ++k) { float e = __expf(attn[k] - mx); attn[k] = e; sum += e; }
        float inv = 1.f / sum;
        for (int k = 0; k < 32; ++k) attn[k] *= inv;
    }
    __syncthreads();
    float a0 = 0.f, a1 = 0.f;
    for (int k = 0; k < 32; ++k) {
        const unsigned short* vrow = V + ((size_t)(r * 32 + k)) * C_ + h * DH_;
        float a = attn[k];
        a0 += a * b2f(vrow[t]);
        a1 += a * b2f(vrow[t + 64]);
    }
    O[qb + t]      = f2b(a0);
    O[qb + t + 64] = f2b(a1);
}

// ---------- LayerNorm: out = LN((masked? 0 : A) + Res) * gamma + beta ----------
__global__ __launch_bounds__(64)
void ln_kernel(const unsigned short* __restrict__ A, const unsigned short* __restrict__ Res,
               const unsigned short* __restrict__ gamma, const unsigned short* __restrict__ beta,
               unsigned short* __restrict__ out, const int* __restrict__ lens, int use_mask) {
    const int m = blockIdx.x;
    const int t = threadIdx.x;
    const bool masked = use_mask && ((m & 31) >= lens[m >> 5]);
    const size_t base = (size_t)m * C_ + t * 8;
    float xa[8], xr[8], x[8];
    unpack8(*(const uint4*)(A + base), xa);
    unpack8(*(const uint4*)(Res + base), xr);
    float s = 0.f, ss = 0.f;
#pragma unroll
    for (int e = 0; e < 8; ++e) {
        x[e] = (masked ? 0.f : xa[e]) + xr[e];
        s += x[e]; ss += x[e] * x[e];
    }
#pragma unroll
    for (int off = 32; off > 0; off >>= 1) {
        s  += __shfl_down(s, off);
        ss += __shfl_down(ss, off);
    }
    s = __shfl(s, 0); ss = __shfl(ss, 0);
    const float mu = s * (1.f / 512.f);
    const float rinv = rsqrtf(fmaxf(ss * (1.f / 512.f) - mu * mu, 0.f) + 1e-5f);
    float gg[8], bb[8], y[8];
    unpack8(*(const uint4*)(gamma + t * 8), gg);
    unpack8(*(const uint4*)(beta + t * 8), bb);
#pragma unroll
    for (int e = 0; e < 8; ++e) y[e] = (x[e] - mu) * rinv * gg[e] + bb[e];
    *(uint4*)(out + base) = pack8(y);
}

extern "C" void kernel_launch(void* const* d_in, const int* in_sizes, int n_in,
                              void* d_out, int out_size, void* d_ws, size_t ws_size,
                              hipStream_t stream) {
    (void)in_sizes; (void)n_in;
    const void* gene = d_in[0];
    const int*  gidx = (const int*)d_in[1];
    const int*  lens = (const int*)d_in[2];

    int* flag = (int*)d_ws;
    unsigned short* ws0 = (unsigned short*)d_ws + 64;  // 128B offset past flag

    size_t off = 0;
    auto take = [&](size_t elems) { unsigned short* p = ws0 + off; off += elems; return p; };
    const size_t WG = (size_t)4 * C_ * C_;
    unsigned short* wQ = take(WG);
    unsigned short* wK = take(WG);
    unsigned short* wV = take(WG);
    unsigned short* wO = take(WG);
    unsigned short* wF = take(WG);
    unsigned short* wP = take((size_t)C_ * C_);
    unsigned short* cbq = take(4 * C_);
    unsigned short* cbk = take(4 * C_);
    unsigned short* cbv = take(4 * C_);
    unsigned short* cbo = take(4 * C_);
    unsigned short* cff = take(4 * C_);
    unsigned short* cg1 = take(4 * C_);
    unsigned short* cb1 = take(4 * C_);
    unsigned short* cg2 = take(4 * C_);
    unsigned short* cb2 = take(4 * C_);
    unsigned short* cpb = take(C_);
    unsigned short* csd = take(C_);
    const size_t wbytes = 128 + off * 2;

    int Rc = 0;
    const int cands[8] = {4096, 2048, 1024, 512, 256, 128, 64, 32};
    for (int i = 0; i < 8; ++i) {
        size_t need = wbytes + (size_t)cands[i] * 135168;
        if (need <= ws_size) { Rc = cands[i]; break; }
    }
    if (Rc == 0) {
        diag_kernel<<<(out_size + 255) / 256, 256, 0, stream>>>(
            (unsigned short*)d_out, out_size, 1000.0f + (float)(ws_size >> 20));
        return;
    }
    const int Mc = Rc * 32;

    unsigned short* X  = take((size_t)Mc * C_);
    unsigned short* A1 = take((size_t)Mc * C_);
    unsigned short* A2 = take((size_t)Mc * C_);
    unsigned short* A3 = take((size_t)Mc * C_);
    unsigned short* S0 = take((size_t)Rc * C_);
    unsigned short* S1 = take((size_t)Rc * C_);
    unsigned short* S2 = take((size_t)Rc * C_);
    unsigned short* S3 = take((size_t)Rc * C_);

    detect_kernel<<<1, 256, 0, stream>>>((const unsigned short*)gene, flag);
    auto cvt = [&](const void* in, unsigned short* out_, int n) {
        cvt_any_kernel<<<(n + 2047) / 2048, 256, 0, stream>>>(in, out_, n, flag);
    };
    cvt(d_in[3], wQ, (int)WG); cvt(d_in[4], wK, (int)WG); cvt(d_in[5], wV, (int)WG);
    cvt(d_in[6], wO, (int)WG); cvt(d_in[7], wF, (int)WG);
    cvt(d_in[17], wP, C_ * C_);
    cvt(d_in[8], cbq, 4 * C_);  cvt(d_in[9], cbk, 4 * C_);  cvt(d_in[10], cbv, 4 * C_);
    cvt(d_in[11], cbo, 4 * C_); cvt(d_in[12], cff, 4 * C_);
    cvt(d_in[13], cg1, 4 * C_); cvt(d_in[14], cb1, 4 * C_);
    cvt(d_in[15], cg2, 4 * C_); cvt(d_in[16], cb2, 4 * C_);
    cvt(d_in[18], cpb, C_);     cvt(d_in[19], csd, C_);

    auto gemm = [&](const unsigned short* Ain, const unsigned short* Win,
                    const unsigned short* bias, unsigned short* Outp, int Mrows, int relu) {
        dim3 grid(Mrows / 128, C_ / 128);
        gemm_bt_kernel<<<grid, 256, 0, stream>>>(Ain, Win, bias, Outp, relu);
    };

    const size_t CC = (size_t)C_ * C_;
    for (int c = 0; c < R_ / Rc; ++c) {
        const int r0 = c * Rc;
        const int* lc = lens + r0;

        gather_kernel<<<Mc * 64 / 256, 256, 0, stream>>>(gene, gidx + (size_t)r0 * L_, lc, X, flag);

        for (int i = 0; i < 2; ++i) {
            const size_t wo_ = (size_t)i * CC;
            gemm(X, wQ + wo_, cbq + i * C_, A1, Mc, 0);
            gemm(X, wK + wo_, cbk + i * C_, A2, Mc, 0);
            gemm(X, wV + wo_, cbv + i * C_, A3, Mc, 0);
            attn_enc_kernel<<<dim3(Rc, H_), 128, 0, stream>>>(A1, A2, A3, A1, lc);
            gemm(A1, wO + wo_, cbo + i * C_, A2, Mc, 0);
            ln_kernel<<<Mc, 64, 0, stream>>>(A2, X, cg1 + i * C_, cb1 + i * C_, X, lc, 1);
            gemm(X, wF + wo_, cff + i * C_, A3, Mc, 1);
            ln_kernel<<<Mc, 64, 0, stream>>>(A3, X, cg2 + i * C_, cb2 + i * C_, X, lc, 0);
        }

        gemm(X, wP, cpb, A1, Mc, 1);
        seed_kernel<<<Rc * 64 / 256, 256, 0, stream>>>(csd, S0);

        {
            const size_t wo_ = (size_t)2 * CC;
            gemm(S0, wQ + wo_, cbq + 2 * C_, S1, Rc, 0);
            gemm(A1, wK + wo_, cbk + 2 * C_, A2, Mc, 0);
            gemm(A1, wV + wo_, cbv + 2 * C_, A3, Mc, 0);
            attn_pma_kernel<<<dim3(Rc, H_), 64, 0, stream>>>(S1, A2, A3, S2, lc);
            gemm(S2, wO + wo_, cbo + 2 * C_, S3, Rc, 0);
            ln_kernel<<<Rc, 64, 0, stream>>>(S3, S0, cg1 + 2 * C_, cb1 + 2 * C_, S0, lc, 0);
            gemm(S0, wF + wo_, cff + 2 * C_, S1, Rc, 1);
            ln_kernel<<<Rc, 64, 0, stream>>>(S1, S0, cg2 + 2 * C_, cb2 + 2 * C_, S0, lc, 0);
        }

        {
            const size_t wo_ = (size_t)3 * CC;
            gemm(S0, wV + wo_, cbv + 3 * C_, S1, Rc, 0);
            gemm(S1, wO + wo_, cbo + 3 * C_, S2, Rc, 0);
            ln_kernel<<<Rc, 64, 0, stream>>>(S2, S0, cg1 + 3 * C_, cb1 + 3 * C_, S0, lc, 0);
            gemm(S0, wF + wo_, cff + 3 * C_, S1, Rc, 1);
            ln_kernel<<<Rc, 64, 0, stream>>>(S1, S0, cg2 + 3 * C_, cb2 + 3 * C_, S0, lc, 0);
        }

        final_kernel<<<Rc * 64 / 256, 256, 0, stream>>>(S0, lc, d_out, flag, (size_t)r0 * C_);
    }
}

// Round 4
// 2906.442 us; speedup vs baseline: 1.3353x; 1.3353x over previous
//
#include <hip/hip_runtime.h>
#include <stdint.h>

#define R_ 4096
#define L_ 32
#define C_ 512
#define H_ 4
#define DH_ 128

typedef __bf16 bf16x8 __attribute__((ext_vector_type(8)));
typedef float f32x4 __attribute__((ext_vector_type(4)));

// ---------- bf16 bit helpers (RNE) ----------
__device__ __forceinline__ float b2f(unsigned int u) {
    union { unsigned int i; float f; } x; x.i = u << 16; return x.f;
}
__device__ __forceinline__ unsigned short f2b(float f) {
    union { float f; unsigned int i; } x; x.f = f;
    unsigned int i = x.i;
    i += 0x7fffu + ((i >> 16) & 1u);
    return (unsigned short)(i >> 16);
}
__device__ __forceinline__ void unpack8(uint4 v, float* x) {
    x[0] = b2f(v.x & 0xffffu); x[1] = b2f(v.x >> 16);
    x[2] = b2f(v.y & 0xffffu); x[3] = b2f(v.y >> 16);
    x[4] = b2f(v.z & 0xffffu); x[5] = b2f(v.z >> 16);
    x[6] = b2f(v.w & 0xffffu); x[7] = b2f(v.w >> 16);
}
__device__ __forceinline__ uint4 pack8(const float* x) {
    uint4 v;
    v.x = (unsigned)f2b(x[0]) | ((unsigned)f2b(x[1]) << 16);
    v.y = (unsigned)f2b(x[2]) | ((unsigned)f2b(x[3]) << 16);
    v.z = (unsigned)f2b(x[4]) | ((unsigned)f2b(x[5]) << 16);
    v.w = (unsigned)f2b(x[6]) | ((unsigned)f2b(x[7]) << 16);
    return v;
}

// async global->LDS, 16B per lane; LDS dest = wave-uniform base + lane*16
__device__ __forceinline__ void gload_lds16(const unsigned short* g, unsigned short* l) {
    __builtin_amdgcn_global_load_lds(
        (const __attribute__((address_space(1))) void*)g,
        (__attribute__((address_space(3))) void*)l, 16, 0, 0);
}

// ---------- dtype detection: 1 = bf16, 0 = fp32 ----------
__global__ __launch_bounds__(256)
void detect_kernel(const unsigned short* __restrict__ gene, int* __restrict__ flag) {
    __shared__ int cnt;
    if (threadIdx.x == 0) cnt = 0;
    __syncthreads();
    int local = 0;
    for (int j = 0; j < 8; ++j) {
        int i = threadIdx.x * 8 + j;
        unsigned short u = gene[2 * i];
        int e = (u >> 7) & 0xFF;
        if (e >= 100 && e <= 140) ++local;
    }
    atomicAdd(&cnt, local);
    __syncthreads();
    if (threadIdx.x == 0) *flag = (cnt >= 1024) ? 1 : 0;
}

// ---------- convert (fp32|bf16) -> bf16, branch on flag ----------
__global__ __launch_bounds__(256)
void cvt_any_kernel(const void* __restrict__ in, unsigned short* __restrict__ out,
                    int n, const int* __restrict__ flag) {
    int i0 = (blockIdx.x * 256 + threadIdx.x) * 8;
    if (i0 >= n) return;
    if (*flag) {
        *(uint4*)(out + i0) = *(const uint4*)((const unsigned short*)in + i0);
    } else {
        const float* f = (const float*)in;
        float4 a = *(const float4*)(f + i0);
        float4 b = *(const float4*)(f + i0 + 4);
        float x[8] = {a.x, a.y, a.z, a.w, b.x, b.y, b.z, b.w};
        *(uint4*)(out + i0) = pack8(x);
    }
}

// ---------- diagnostic ----------
__global__ __launch_bounds__(256)
void diag_kernel(unsigned short* __restrict__ out, int n, float val) {
    int i = blockIdx.x * 256 + threadIdx.x;
    if (i < n) out[i] = f2b(val);
}

// ---------- gather genes -> X [Mc, C] bf16, masked rows = 0 ----------
__global__ __launch_bounds__(256)
void gather_kernel(const void* __restrict__ gene_v, const int* __restrict__ gidx,
                   const int* __restrict__ lens, unsigned short* __restrict__ X,
                   const int* __restrict__ flag) {
    int tid = blockIdx.x * 256 + threadIdx.x;
    int m = tid >> 6;
    int ch = tid & 63;
    uint4 v = make_uint4(0u, 0u, 0u, 0u);
    if ((m & 31) < lens[m >> 5]) {
        size_t base = (size_t)gidx[m] * C_ + ch * 8;
        if (*flag) {
            v = *(const uint4*)((const unsigned short*)gene_v + base);
        } else {
            const float* f = (const float*)gene_v;
            float4 a = *(const float4*)(f + base);
            float4 b = *(const float4*)(f + base + 4);
            float x[8] = {a.x, a.y, a.z, a.w, b.x, b.y, b.z, b.w};
            v = pack8(x);
        }
    }
    *(uint4*)(X + (size_t)m * C_ + ch * 8) = v;
}

// ---------- seed broadcast -> Xs [Rc, C] bf16 ----------
__global__ __launch_bounds__(256)
void seed_kernel(const unsigned short* __restrict__ seed, unsigned short* __restrict__ Xs) {
    int i = blockIdx.x * 256 + threadIdx.x;
    int ch = i & 63;
    uint4 v = *(const uint4*)(seed + ch * 8);
    *(uint4*)(Xs + (size_t)i * 8) = v;
}

// ---------- final: S0 bf16 -> out (bf16|fp32 per flag), zero empty reactions ----------
__global__ __launch_bounds__(256)
void final_kernel(const unsigned short* __restrict__ S, const int* __restrict__ lens,
                  void* __restrict__ out, const int* __restrict__ flag, size_t elem_off) {
    int i = blockIdx.x * 256 + threadIdx.x;
    int r = i >> 6;
    uint4 v = make_uint4(0u, 0u, 0u, 0u);
    if (lens[r] > 0) v = *(const uint4*)(S + (size_t)i * 8);
    if (*flag) {
        *(uint4*)((unsigned short*)out + elem_off + (size_t)i * 8) = v;
    } else {
        float x[8];
        unpack8(v, x);
        float* o = (float*)out + elem_off + (size_t)i * 8;
        *(float4*)o       = make_float4(x[0], x[1], x[2], x[3]);
        *(float4*)(o + 4) = make_float4(x[4], x[5], x[6], x[7]);
    }
}

// ---------- GEMM (m97 structure): Out[M,512] = A @ W^T + bias, opt ReLU ----------
// 128x128 tile, BK=32, 4 waves, global_load_lds 16B staging (unpadded LDS).
__global__ __launch_bounds__(256)
void gemm_bt_kernel(const unsigned short* __restrict__ A, const unsigned short* __restrict__ W,
                    const unsigned short* __restrict__ bias, unsigned short* __restrict__ Out,
                    int relu) {
    __shared__ unsigned short As[128 * 32];
    __shared__ unsigned short Bs[128 * 32];

    const int t = threadIdx.x;
    const int wave = t >> 6, lane = t & 63;
    const int quad = lane >> 4, lr = lane & 15;
    const int wr = wave >> 1, wc = wave & 1;
    const int m0 = blockIdx.x * 128, n0 = blockIdx.y * 128;

    // staging map: wave-instr j covers rows (wave+4j)*16..+16, lane l -> row +l/4, col (l&3)*8
    const int srow = wave * 16 + (lane >> 2);
    const int scol = (lane & 3) * 8;
    const unsigned short* ga0 = A + (size_t)(m0 + srow) * C_ + scol;
    const unsigned short* ga1 = A + (size_t)(m0 + srow + 64) * C_ + scol;
    const unsigned short* gb0 = W + (size_t)(n0 + srow) * C_ + scol;
    const unsigned short* gb1 = W + (size_t)(n0 + srow + 64) * C_ + scol;
    unsigned short* lA0 = As + wave * 512;
    unsigned short* lA1 = As + (wave + 4) * 512;
    unsigned short* lB0 = Bs + wave * 512;
    unsigned short* lB1 = Bs + (wave + 4) * 512;

    f32x4 acc[4][4] = {};

    for (int k0 = 0; k0 < C_; k0 += 32) {
        __syncthreads();                       // prior ds_reads drained before overwrite
        gload_lds16(ga0 + k0, lA0);
        gload_lds16(ga1 + k0, lA1);
        gload_lds16(gb0 + k0, lB0);
        gload_lds16(gb1 + k0, lB1);
        __syncthreads();                       // vmcnt(0) drain -> LDS populated

        bf16x8 af[4], bfr[4];
#pragma unroll
        for (int i = 0; i < 4; ++i)
            af[i] = *(const bf16x8*)&As[(64 * wr + 16 * i + lr) * 32 + quad * 8];
#pragma unroll
        for (int j = 0; j < 4; ++j)
            bfr[j] = *(const bf16x8*)&Bs[(64 * wc + 16 * j + lr) * 32 + quad * 8];
#pragma unroll
        for (int i = 0; i < 4; ++i)
#pragma unroll
            for (int j = 0; j < 4; ++j)
                acc[i][j] = __builtin_amdgcn_mfma_f32_16x16x32_bf16(af[i], bfr[j], acc[i][j], 0, 0, 0);
    }

#pragma unroll
    for (int i = 0; i < 4; ++i) {
        int row = m0 + 64 * wr + 16 * i + quad * 4;
#pragma unroll
        for (int j = 0; j < 4; ++j) {
            int col = n0 + 64 * wc + 16 * j + lr;
            float bv = b2f(bias[col]);
#pragma unroll
            for (int r = 0; r < 4; ++r) {
                float v = acc[i][j][r] + bv;
                if (relu) v = fmaxf(v, 0.f);
                Out[(size_t)(row + r) * C_ + col] = f2b(v);
            }
        }
    }
}

// ---------- encoder attention: per (r,h), Lq=Lk=32, key mask ----------
// QK: thread=(qg 0..15, kg 0..7) -> 2q x 4k, conflict-free (odd row stride).
// AV: thread=(qh 0..15, g 0..7) -> 2q x 16d with d=g*8+e+64j (bank spread 8: free).
__global__ __launch_bounds__(128)
void attn_enc_kernel(const unsigned short* __restrict__ Q, const unsigned short* __restrict__ K,
                     const unsigned short* __restrict__ V, unsigned short* __restrict__ O,
                     const int* __restrict__ lens) {
    const int r = blockIdx.x, h = blockIdx.y, t = threadIdx.x;
    __shared__ float Qs[32][129], Ks[32][129], Vs[32][129];
    __shared__ float Sc[32][33];
    const int len = lens[r];

    for (int it = 0; it < 4; ++it) {
        int flat = t + it * 128;            // 512 chunks of 8
        int row = flat >> 4, ch = flat & 15;
        size_t g = ((size_t)(r * 32 + row)) * C_ + h * DH_ + ch * 8;
        float xq[8], xk[8], xv[8];
        unpack8(*(const uint4*)(Q + g), xq);
        unpack8(*(const uint4*)(K + g), xk);
        unpack8(*(const uint4*)(V + g), xv);
#pragma unroll
        for (int e = 0; e < 8; ++e) {
            Qs[row][ch * 8 + e] = xq[e];
            Ks[row][ch * 8 + e] = xk[e];
            Vs[row][ch * 8 + e] = xv[e];
        }
    }
    __syncthreads();

    {   // QK^T
        const int qg = t >> 3, kg = t & 7;
        float aqk[2][4] = {};
        for (int d = 0; d < 128; ++d) {
            float q0 = Qs[2 * qg][d], q1 = Qs[2 * qg + 1][d];
#pragma unroll
            for (int i = 0; i < 4; ++i) {
                float kv = Ks[4 * kg + i][d];
                aqk[0][i] += q0 * kv;
                aqk[1][i] += q1 * kv;
            }
        }
        const float scale = 0.08838834764831845f;  // 1/sqrt(128)
#pragma unroll
        for (int j = 0; j < 2; ++j)
#pragma unroll
            for (int i = 0; i < 4; ++i) {
                int k = 4 * kg + i;
                Sc[2 * qg + j][k] = (k < len) ? aqk[j][i] * scale : -1e30f;
            }
    }
    __syncthreads();

    if (t < 32) {
        float mx = -3e38f;
        for (int k = 0; k < 32; ++k) mx = fmaxf(mx, Sc[t][k]);
        float sum = 0.f;
        for (int k = 0; k < 32; ++k) { float e = __expf(Sc[t][k] - mx); Sc[t][k] = e; sum += e; }
        float inv = 1.f / sum;
        for (int k = 0; k < 32; ++k) Sc[t][k] *= inv;
    }
    __syncthreads();

    {   // AV
        const int qh = t >> 3, g = t & 7;
        float av[2][16] = {};
        for (int k = 0; k < 32; ++k) {
            float a0 = Sc[2 * qh][k], a1 = Sc[2 * qh + 1][k];
#pragma unroll
            for (int j = 0; j < 2; ++j)
#pragma unroll
                for (int e = 0; e < 8; ++e) {
                    float v = Vs[k][g * 8 + 64 * j + e];
                    av[0][j * 8 + e] += a0 * v;
                    av[1][j * 8 + e] += a1 * v;
                }
        }
#pragma unroll
        for (int qi = 0; qi < 2; ++qi) {
            int q = 2 * qh + qi;
            size_t ga = ((size_t)(r * 32 + q)) * C_ + h * DH_;
#pragma unroll
            for (int j = 0; j < 2; ++j) {
                float tmp[8];
#pragma unroll
                for (int e = 0; e < 8; ++e) tmp[e] = av[qi][j * 8 + e];
                *(uint4*)(O + ga + g * 8 + 64 * j) = pack8(tmp);
            }
        }
    }
}

// ---------- PMA attention: per (r,h), 1 query (seed), 32 keys, key mask ----------
__global__ __launch_bounds__(64)
void attn_pma_kernel(const unsigned short* __restrict__ Qs_, const unsigned short* __restrict__ K,
                     const unsigned short* __restrict__ V, unsigned short* __restrict__ O,
                     const int* __restrict__ lens) {
    const int r = blockIdx.x, h = blockIdx.y, t = threadIdx.x;
    __shared__ float qv[128];
    __shared__ float attn[32];
    const int len = lens[r];
    const size_t qb = (size_t)r * C_ + h * DH_;
    qv[t]      = b2f(Qs_[qb + t]);
    qv[t + 64] = b2f(Qs_[qb + t + 64]);
    __syncthreads();
    if (t < 32) {
        const unsigned short* krow = K + ((size_t)(r * 32 + t)) * C_ + h * DH_;
        float s = 0.f;
        for (int d = 0; d < 128; ++d) s += qv[d] * b2f(krow[d]);
        attn[t] = (t < len) ? s * 0.08838834764831845f : -1e30f;
    }
    __syncthreads();
    if (t == 0) {
        float mx = -3e38f;
        for (int k = 0; k < 32; ++k) mx = fmaxf(mx, attn[k]);
        float sum = 0.f;
        for (int k = 0; k < 32; ++k) { float e = __expf(attn[k] - mx); attn[k] = e; sum += e; }
        float inv = 1.f / sum;
        for (int k = 0; k < 32; ++k) attn[k] *= inv;
    }
    __syncthreads();
    float a0 = 0.f, a1 = 0.f;
    for (int k = 0; k < 32; ++k) {
        const unsigned short* vrow = V + ((size_t)(r * 32 + k)) * C_ + h * DH_;
        float a = attn[k];
        a0 += a * b2f(vrow[t]);
        a1 += a * b2f(vrow[t + 64]);
    }
    O[qb + t]      = f2b(a0);
    O[qb + t + 64] = f2b(a1);
}

// ---------- LayerNorm: 4 rows/block (1 wave each) ----------
__global__ __launch_bounds__(256)
void ln_kernel(const unsigned short* __restrict__ A, const unsigned short* __restrict__ Res,
               const unsigned short* __restrict__ gamma, const unsigned short* __restrict__ beta,
               unsigned short* __restrict__ out, const int* __restrict__ lens, int use_mask) {
    const int m = blockIdx.x * 4 + (threadIdx.x >> 6);
    const int lane = threadIdx.x & 63;
    const bool masked = use_mask && ((m & 31) >= lens[m >> 5]);
    const size_t base = (size_t)m * C_ + lane * 8;
    float xa[8], xr[8], x[8];
    unpack8(*(const uint4*)(A + base), xa);
    unpack8(*(const uint4*)(Res + base), xr);
    float s = 0.f, ss = 0.f;
#pragma unroll
    for (int e = 0; e < 8; ++e) {
        x[e] = (masked ? 0.f : xa[e]) + xr[e];
        s += x[e]; ss += x[e] * x[e];
    }
#pragma unroll
    for (int off = 32; off > 0; off >>= 1) {
        s  += __shfl_down(s, off);
        ss += __shfl_down(ss, off);
    }
    s = __shfl(s, 0); ss = __shfl(ss, 0);
    const float mu = s * (1.f / 512.f);
    const float rinv = rsqrtf(fmaxf(ss * (1.f / 512.f) - mu * mu, 0.f) + 1e-5f);
    float gg[8], bb[8], y[8];
    unpack8(*(const uint4*)(gamma + lane * 8), gg);
    unpack8(*(const uint4*)(beta + lane * 8), bb);
#pragma unroll
    for (int e = 0; e < 8; ++e) y[e] = (x[e] - mu) * rinv * gg[e] + bb[e];
    *(uint4*)(out + base) = pack8(y);
}

extern "C" void kernel_launch(void* const* d_in, const int* in_sizes, int n_in,
                              void* d_out, int out_size, void* d_ws, size_t ws_size,
                              hipStream_t stream) {
    (void)in_sizes; (void)n_in;
    const void* gene = d_in[0];
    const int*  gidx = (const int*)d_in[1];
    const int*  lens = (const int*)d_in[2];

    int* flag = (int*)d_ws;
    unsigned short* ws0 = (unsigned short*)d_ws + 64;

    size_t off = 0;
    auto take = [&](size_t elems) { unsigned short* p = ws0 + off; off += elems; return p; };
    const size_t WG = (size_t)4 * C_ * C_;
    unsigned short* wQ = take(WG);
    unsigned short* wK = take(WG);
    unsigned short* wV = take(WG);
    unsigned short* wO = take(WG);
    unsigned short* wF = take(WG);
    unsigned short* wP = take((size_t)C_ * C_);
    unsigned short* cbq = take(4 * C_);
    unsigned short* cbk = take(4 * C_);
    unsigned short* cbv = take(4 * C_);
    unsigned short* cbo = take(4 * C_);
    unsigned short* cff = take(4 * C_);
    unsigned short* cg1 = take(4 * C_);
    unsigned short* cb1 = take(4 * C_);
    unsigned short* cg2 = take(4 * C_);
    unsigned short* cb2 = take(4 * C_);
    unsigned short* cpb = take(C_);
    unsigned short* csd = take(C_);
    const size_t wbytes = 128 + off * 2;

    int Rc = 0;
    const int cands[8] = {4096, 2048, 1024, 512, 256, 128, 64, 32};
    for (int i = 0; i < 8; ++i) {
        size_t need = wbytes + (size_t)cands[i] * 135168;
        if (need <= ws_size) { Rc = cands[i]; break; }
    }
    if (Rc == 0) {
        diag_kernel<<<(out_size + 255) / 256, 256, 0, stream>>>(
            (unsigned short*)d_out, out_size, 1000.0f + (float)(ws_size >> 20));
        return;
    }
    const int Mc = Rc * 32;

    unsigned short* X  = take((size_t)Mc * C_);
    unsigned short* A1 = take((size_t)Mc * C_);
    unsigned short* A2 = take((size_t)Mc * C_);
    unsigned short* A3 = take((size_t)Mc * C_);
    unsigned short* S0 = take((size_t)Rc * C_);
    unsigned short* S1 = take((size_t)Rc * C_);
    unsigned short* S2 = take((size_t)Rc * C_);
    unsigned short* S3 = take((size_t)Rc * C_);

    detect_kernel<<<1, 256, 0, stream>>>((const unsigned short*)gene, flag);
    auto cvt = [&](const void* in, unsigned short* out_, int n) {
        cvt_any_kernel<<<(n + 2047) / 2048, 256, 0, stream>>>(in, out_, n, flag);
    };
    cvt(d_in[3], wQ, (int)WG); cvt(d_in[4], wK, (int)WG); cvt(d_in[5], wV, (int)WG);
    cvt(d_in[6], wO, (int)WG); cvt(d_in[7], wF, (int)WG);
    cvt(d_in[17], wP, C_ * C_);
    cvt(d_in[8], cbq, 4 * C_);  cvt(d_in[9], cbk, 4 * C_);  cvt(d_in[10], cbv, 4 * C_);
    cvt(d_in[11], cbo, 4 * C_); cvt(d_in[12], cff, 4 * C_);
    cvt(d_in[13], cg1, 4 * C_); cvt(d_in[14], cb1, 4 * C_);
    cvt(d_in[15], cg2, 4 * C_); cvt(d_in[16], cb2, 4 * C_);
    cvt(d_in[18], cpb, C_);     cvt(d_in[19], csd, C_);

    auto gemm = [&](const unsigned short* Ain, const unsigned short* Win,
                    const unsigned short* bias, unsigned short* Outp, int Mrows, int relu) {
        dim3 grid(Mrows / 128, C_ / 128);
        gemm_bt_kernel<<<grid, 256, 0, stream>>>(Ain, Win, bias, Outp, relu);
    };

    const size_t CC = (size_t)C_ * C_;
    for (int c = 0; c < R_ / Rc; ++c) {
        const int r0 = c * Rc;
        const int* lc = lens + r0;

        gather_kernel<<<Mc * 64 / 256, 256, 0, stream>>>(gene, gidx + (size_t)r0 * L_, lc, X, flag);

        for (int i = 0; i < 2; ++i) {
            const size_t wo_ = (size_t)i * CC;
            gemm(X, wQ + wo_, cbq + i * C_, A1, Mc, 0);
            gemm(X, wK + wo_, cbk + i * C_, A2, Mc, 0);
            gemm(X, wV + wo_, cbv + i * C_, A3, Mc, 0);
            attn_enc_kernel<<<dim3(Rc, H_), 128, 0, stream>>>(A1, A2, A3, A1, lc);
            gemm(A1, wO + wo_, cbo + i * C_, A2, Mc, 0);
            ln_kernel<<<Mc / 4, 256, 0, stream>>>(A2, X, cg1 + i * C_, cb1 + i * C_, X, lc, 1);
            gemm(X, wF + wo_, cff + i * C_, A3, Mc, 1);
            ln_kernel<<<Mc / 4, 256, 0, stream>>>(A3, X, cg2 + i * C_, cb2 + i * C_, X, lc, 0);
        }

        gemm(X, wP, cpb, A1, Mc, 1);
        seed_kernel<<<Rc * 64 / 256, 256, 0, stream>>>(csd, S0);

        {
            const size_t wo_ = (size_t)2 * CC;
            gemm(S0, wQ + wo_, cbq + 2 * C_, S1, Rc, 0);
            gemm(A1, wK + wo_, cbk + 2 * C_, A2, Mc, 0);
            gemm(A1, wV + wo_, cbv + 2 * C_, A3, Mc, 0);
            attn_pma_kernel<<<dim3(Rc, H_), 64, 0, stream>>>(S1, A2, A3, S2, lc);
            gemm(S2, wO + wo_, cbo + 2 * C_, S3, Rc, 0);
            ln_kernel<<<Rc / 4, 256, 0, stream>>>(S3, S0, cg1 + 2 * C_, cb1 + 2 * C_, S0, lc, 0);
            gemm(S0, wF + wo_, cff + 2 * C_, S1, Rc, 1);
            ln_kernel<<<Rc / 4, 256, 0, stream>>>(S1, S0, cg2 + 2 * C_, cb2 + 2 * C_, S0, lc, 0);
        }

        {
            const size_t wo_ = (size_t)3 * CC;
            gemm(S0, wV + wo_, cbv + 3 * C_, S1, Rc, 0);
            gemm(S1, wO + wo_, cbo + 3 * C_, S2, Rc, 0);
            ln_kernel<<<Rc / 4, 256, 0, stream>>>(S2, S0, cg1 + 3 * C_, cb1 + 3 * C_, S0, lc, 0);
            gemm(S0, wF + wo_, cff + 3 * C_, S1, Rc, 1);
            ln_kernel<<<Rc / 4, 256, 0, stream>>>(S1, S0, cg2 + 3 * C_, cb2 + 3 * C_, S0, lc, 0);
        }

        final_kernel<<<Rc * 64 / 256, 256, 0, stream>>>(S0, lc, d_out, flag, (size_t)r0 * C_);
    }
}

// Round 5
// 2683.024 us; speedup vs baseline: 1.4465x; 1.0833x over previous
//
#include <hip/hip_runtime.h>
#include <stdint.h>

#define R_ 4096
#define L_ 32
#define C_ 512
#define H_ 4
#define DH_ 128

typedef __bf16 bf16x8 __attribute__((ext_vector_type(8)));
typedef float f32x4 __attribute__((ext_vector_type(4)));

// ---------- bf16 bit helpers (RNE) ----------
__device__ __forceinline__ float b2f(unsigned int u) {
    union { unsigned int i; float f; } x; x.i = u << 16; return x.f;
}
__device__ __forceinline__ unsigned short f2b(float f) {
    union { float f; unsigned int i; } x; x.f = f;
    unsigned int i = x.i;
    i += 0x7fffu + ((i >> 16) & 1u);
    return (unsigned short)(i >> 16);
}
__device__ __forceinline__ void unpack8(uint4 v, float* x) {
    x[0] = b2f(v.x & 0xffffu); x[1] = b2f(v.x >> 16);
    x[2] = b2f(v.y & 0xffffu); x[3] = b2f(v.y >> 16);
    x[4] = b2f(v.z & 0xffffu); x[5] = b2f(v.z >> 16);
    x[6] = b2f(v.w & 0xffffu); x[7] = b2f(v.w >> 16);
}
__device__ __forceinline__ uint4 pack8(const float* x) {
    uint4 v;
    v.x = (unsigned)f2b(x[0]) | ((unsigned)f2b(x[1]) << 16);
    v.y = (unsigned)f2b(x[2]) | ((unsigned)f2b(x[3]) << 16);
    v.z = (unsigned)f2b(x[4]) | ((unsigned)f2b(x[5]) << 16);
    v.w = (unsigned)f2b(x[6]) | ((unsigned)f2b(x[7]) << 16);
    return v;
}

// async global->LDS, 16B per lane; LDS dest = wave-uniform base + lane*16
__device__ __forceinline__ void gload_lds16(const unsigned short* g, unsigned short* l) {
    __builtin_amdgcn_global_load_lds(
        (const __attribute__((address_space(1))) void*)g,
        (__attribute__((address_space(3))) void*)l, 16, 0, 0);
}

// ---------- dtype detection: 1 = bf16, 0 = fp32 ----------
__global__ __launch_bounds__(256)
void detect_kernel(const unsigned short* __restrict__ gene, int* __restrict__ flag) {
    __shared__ int cnt;
    if (threadIdx.x == 0) cnt = 0;
    __syncthreads();
    int local = 0;
    for (int j = 0; j < 8; ++j) {
        int i = threadIdx.x * 8 + j;
        unsigned short u = gene[2 * i];
        int e = (u >> 7) & 0xFF;
        if (e >= 100 && e <= 140) ++local;
    }
    atomicAdd(&cnt, local);
    __syncthreads();
    if (threadIdx.x == 0) *flag = (cnt >= 1024) ? 1 : 0;
}

// ---------- convert (fp32|bf16) -> bf16, branch on flag ----------
__global__ __launch_bounds__(256)
void cvt_any_kernel(const void* __restrict__ in, unsigned short* __restrict__ out,
                    int n, const int* __restrict__ flag) {
    int i0 = (blockIdx.x * 256 + threadIdx.x) * 8;
    if (i0 >= n) return;
    if (*flag) {
        *(uint4*)(out + i0) = *(const uint4*)((const unsigned short*)in + i0);
    } else {
        const float* f = (const float*)in;
        float4 a = *(const float4*)(f + i0);
        float4 b = *(const float4*)(f + i0 + 4);
        float x[8] = {a.x, a.y, a.z, a.w, b.x, b.y, b.z, b.w};
        *(uint4*)(out + i0) = pack8(x);
    }
}

// ---------- diagnostic ----------
__global__ __launch_bounds__(256)
void diag_kernel(unsigned short* __restrict__ out, int n, float val) {
    int i = blockIdx.x * 256 + threadIdx.x;
    if (i < n) out[i] = f2b(val);
}

// ---------- gather genes -> X [Mc, C] bf16, masked rows = 0 ----------
__global__ __launch_bounds__(256)
void gather_kernel(const void* __restrict__ gene_v, const int* __restrict__ gidx,
                   const int* __restrict__ lens, unsigned short* __restrict__ X,
                   const int* __restrict__ flag) {
    int tid = blockIdx.x * 256 + threadIdx.x;
    int m = tid >> 6;
    int ch = tid & 63;
    uint4 v = make_uint4(0u, 0u, 0u, 0u);
    if ((m & 31) < lens[m >> 5]) {
        size_t base = (size_t)gidx[m] * C_ + ch * 8;
        if (*flag) {
            v = *(const uint4*)((const unsigned short*)gene_v + base);
        } else {
            const float* f = (const float*)gene_v;
            float4 a = *(const float4*)(f + base);
            float4 b = *(const float4*)(f + base + 4);
            float x[8] = {a.x, a.y, a.z, a.w, b.x, b.y, b.z, b.w};
            v = pack8(x);
        }
    }
    *(uint4*)(X + (size_t)m * C_ + ch * 8) = v;
}

// ---------- seed broadcast -> Xs [Rc, C] bf16 ----------
__global__ __launch_bounds__(256)
void seed_kernel(const unsigned short* __restrict__ seed, unsigned short* __restrict__ Xs) {
    int i = blockIdx.x * 256 + threadIdx.x;
    int ch = i & 63;
    uint4 v = *(const uint4*)(seed + ch * 8);
    *(uint4*)(Xs + (size_t)i * 8) = v;
}

// ---------- final: S0 bf16 -> out (bf16|fp32 per flag), zero empty reactions ----------
__global__ __launch_bounds__(256)
void final_kernel(const unsigned short* __restrict__ S, const int* __restrict__ lens,
                  void* __restrict__ out, const int* __restrict__ flag, size_t elem_off) {
    int i = blockIdx.x * 256 + threadIdx.x;
    int r = i >> 6;
    uint4 v = make_uint4(0u, 0u, 0u, 0u);
    if (lens[r] > 0) v = *(const uint4*)(S + (size_t)i * 8);
    if (*flag) {
        *(uint4*)((unsigned short*)out + elem_off + (size_t)i * 8) = v;
    } else {
        float x[8];
        unpack8(v, x);
        float* o = (float*)out + elem_off + (size_t)i * 8;
        *(float4*)o       = make_float4(x[0], x[1], x[2], x[3]);
        *(float4*)(o + 4) = make_float4(x[4], x[5], x[6], x[7]);
    }
}

// ---------- GEMM: Out[M,512] = A @ W^T + bias, opt ReLU ----------
// 128x256 tile, BK=32, 4 waves (2x2 of 64x128), global_load_lds 16B staging.
// Wide-N tile halves A refetch (M >> N regime); 32 MFMA/wave per K-step.
__global__ __launch_bounds__(256, 2)
void gemm_bt_kernel(const unsigned short* __restrict__ A, const unsigned short* __restrict__ W,
                    const unsigned short* __restrict__ bias, unsigned short* __restrict__ Out,
                    int relu) {
    __shared__ unsigned short As[128 * 32];
    __shared__ unsigned short Bs[256 * 32];

    const int t = threadIdx.x;
    const int wave = t >> 6, lane = t & 63;
    const int quad = lane >> 4, lr = lane & 15;
    const int wr = wave >> 1, wc = wave & 1;
    const int m0 = blockIdx.x * 128, n0 = blockIdx.y * 256;

    const int srow = wave * 16 + (lane >> 2);
    const int scol = (lane & 3) * 8;
    const unsigned short* ga0 = A + (size_t)(m0 + srow) * C_ + scol;
    const unsigned short* ga1 = A + (size_t)(m0 + srow + 64) * C_ + scol;
    const unsigned short* gb0 = W + (size_t)(n0 + srow) * C_ + scol;
    const unsigned short* gb1 = W + (size_t)(n0 + srow + 64) * C_ + scol;
    const unsigned short* gb2 = W + (size_t)(n0 + srow + 128) * C_ + scol;
    const unsigned short* gb3 = W + (size_t)(n0 + srow + 192) * C_ + scol;
    unsigned short* lA0 = As + wave * 512;
    unsigned short* lA1 = As + (wave + 4) * 512;
    unsigned short* lB0 = Bs + wave * 512;
    unsigned short* lB1 = Bs + (wave + 4) * 512;
    unsigned short* lB2 = Bs + (wave + 8) * 512;
    unsigned short* lB3 = Bs + (wave + 12) * 512;

    f32x4 acc[4][8] = {};

    for (int k0 = 0; k0 < C_; k0 += 32) {
        __syncthreads();
        gload_lds16(ga0 + k0, lA0);
        gload_lds16(ga1 + k0, lA1);
        gload_lds16(gb0 + k0, lB0);
        gload_lds16(gb1 + k0, lB1);
        gload_lds16(gb2 + k0, lB2);
        gload_lds16(gb3 + k0, lB3);
        __syncthreads();

        bf16x8 af[4], bfr[8];
#pragma unroll
        for (int i = 0; i < 4; ++i)
            af[i] = *(const bf16x8*)&As[(64 * wr + 16 * i + lr) * 32 + quad * 8];
#pragma unroll
        for (int j = 0; j < 8; ++j)
            bfr[j] = *(const bf16x8*)&Bs[(128 * wc + 16 * j + lr) * 32 + quad * 8];
#pragma unroll
        for (int i = 0; i < 4; ++i)
#pragma unroll
            for (int j = 0; j < 8; ++j)
                acc[i][j] = __builtin_amdgcn_mfma_f32_16x16x32_bf16(af[i], bfr[j], acc[i][j], 0, 0, 0);
    }

#pragma unroll
    for (int i = 0; i < 4; ++i) {
        int row = m0 + 64 * wr + 16 * i + quad * 4;
#pragma unroll
        for (int j = 0; j < 8; ++j) {
            int col = n0 + 128 * wc + 16 * j + lr;
            float bv = b2f(bias[col]);
#pragma unroll
            for (int r = 0; r < 4; ++r) {
                float v = acc[i][j][r] + bv;
                if (relu) v = fmaxf(v, 0.f);
                Out[(size_t)(row + r) * C_ + col] = f2b(v);
            }
        }
    }
}

// ---------- encoder attention: per (r,h), Lq=Lk=32, key mask ----------
// bf16 LDS (stride 136 ushorts = 16B-aligned rows, word stride 68 == 4 mod 32).
// QK: thread (qg 0..15, kg 0..7) -> q rows {qg,qg+16} (2-way bank, free),
//     k rows {kg+8i} (conflict-free). AV: q rows {qh,qh+16}, V broadcast reads.
__global__ __launch_bounds__(128)
void attn_enc_kernel(const unsigned short* __restrict__ Q, const unsigned short* __restrict__ K,
                     const unsigned short* __restrict__ V, unsigned short* __restrict__ O,
                     const int* __restrict__ lens) {
    const int r = blockIdx.x, h = blockIdx.y, t = threadIdx.x;
    __shared__ unsigned short Qs[32 * 136], Ks[32 * 136], Vs[32 * 136];
    __shared__ float Sc[32][33];
    const int len = lens[r];

    for (int it = 0; it < 4; ++it) {
        int flat = t + it * 128;            // 512 chunks of 8 ushorts
        int row = flat >> 4, ch = flat & 15;
        size_t g = ((size_t)(r * 32 + row)) * C_ + h * DH_ + ch * 8;
        *(uint4*)&Qs[row * 136 + ch * 8] = *(const uint4*)(Q + g);
        *(uint4*)&Ks[row * 136 + ch * 8] = *(const uint4*)(K + g);
        *(uint4*)&Vs[row * 136 + ch * 8] = *(const uint4*)(V + g);
    }
    __syncthreads();

    const unsigned* Qw = (const unsigned*)Qs;
    const unsigned* Kw = (const unsigned*)Ks;
    const unsigned* Vw = (const unsigned*)Vs;

    {   // QK^T
        const int qg = t >> 3, kg = t & 7;
        float aqk[2][4] = {};
        for (int d2 = 0; d2 < 64; ++d2) {
            unsigned q0 = Qw[qg * 68 + d2];
            unsigned q1 = Qw[(qg + 16) * 68 + d2];
            float q0l = b2f(q0 & 0xffffu), q0h = b2f(q0 >> 16);
            float q1l = b2f(q1 & 0xffffu), q1h = b2f(q1 >> 16);
#pragma unroll
            for (int i = 0; i < 4; ++i) {
                unsigned kv = Kw[(kg + 8 * i) * 68 + d2];
                float kl = b2f(kv & 0xffffu), kh = b2f(kv >> 16);
                aqk[0][i] += q0l * kl + q0h * kh;
                aqk[1][i] += q1l * kl + q1h * kh;
            }
        }
        const float scale = 0.08838834764831845f;  // 1/sqrt(128)
#pragma unroll
        for (int j = 0; j < 2; ++j)
#pragma unroll
            for (int i = 0; i < 4; ++i) {
                int k = kg + 8 * i;
                Sc[qg + 16 * j][k] = (k < len) ? aqk[j][i] * scale : -1e30f;
            }
    }
    __syncthreads();

    if (t < 32) {
        float mx = -3e38f;
        for (int k = 0; k < 32; ++k) mx = fmaxf(mx, Sc[t][k]);
        float sum = 0.f;
        for (int k = 0; k < 32; ++k) { float e = __expf(Sc[t][k] - mx); Sc[t][k] = e; sum += e; }
        float inv = 1.f / sum;
        for (int k = 0; k < 32; ++k) Sc[t][k] *= inv;
    }
    __syncthreads();

    {   // AV
        const int qh = t >> 3, g = t & 7;
        float av[2][16] = {};
        for (int k = 0; k < 32; ++k) {
            float a0 = Sc[qh][k], a1 = Sc[qh + 16][k];
            const unsigned* vrow = Vw + k * 68 + g * 4;
#pragma unroll
            for (int j = 0; j < 2; ++j)
#pragma unroll
                for (int e2 = 0; e2 < 4; ++e2) {
                    unsigned v = vrow[32 * j + e2];
                    float vl = b2f(v & 0xffffu), vh = b2f(v >> 16);
                    av[0][j * 8 + 2 * e2]     += a0 * vl;
                    av[0][j * 8 + 2 * e2 + 1] += a0 * vh;
                    av[1][j * 8 + 2 * e2]     += a1 * vl;
                    av[1][j * 8 + 2 * e2 + 1] += a1 * vh;
                }
        }
#pragma unroll
        for (int qi = 0; qi < 2; ++qi) {
            int q = qh + 16 * qi;
            size_t ga = ((size_t)(r * 32 + q)) * C_ + h * DH_;
#pragma unroll
            for (int j = 0; j < 2; ++j) {
                float tmp[8];
#pragma unroll
                for (int e = 0; e < 8; ++e) tmp[e] = av[qi][j * 8 + e];
                *(uint4*)(O + ga + g * 8 + 64 * j) = pack8(tmp);
            }
        }
    }
}

// ---------- PMA attention: per (r,h), 1 query (seed), 32 keys, key mask ----------
__global__ __launch_bounds__(64)
void attn_pma_kernel(const unsigned short* __restrict__ Qs_, const unsigned short* __restrict__ K,
                     const unsigned short* __restrict__ V, unsigned short* __restrict__ O,
                     const int* __restrict__ lens) {
    const int r = blockIdx.x, h = blockIdx.y, t = threadIdx.x;
    __shared__ float qv[128];
    __shared__ float attn[32];
    const int len = lens[r];
    const size_t qb = (size_t)r * C_ + h * DH_;
    qv[t]      = b2f(Qs_[qb + t]);
    qv[t + 64] = b2f(Qs_[qb + t + 64]);
    __syncthreads();
    if (t < 32) {
        const unsigned short* krow = K + ((size_t)(r * 32 + t)) * C_ + h * DH_;
        float s = 0.f;
        for (int d = 0; d < 128; ++d) s += qv[d] * b2f(krow[d]);
        attn[t] = (t < len) ? s * 0.08838834764831845f : -1e30f;
    }
    __syncthreads();
    if (t == 0) {
        float mx = -3e38f;
        for (int k = 0; k < 32; ++k) mx = fmaxf(mx, attn[k]);
        float sum = 0.f;
        for (int k = 0; k < 32; ++k) { float e = __expf(attn[k] - mx); attn[k] = e; sum += e; }
        float inv = 1.f / sum;
        for (int k = 0; k < 32; ++k) attn[k] *= inv;
    }
    __syncthreads();
    float a0 = 0.f, a1 = 0.f;
    for (int k = 0; k < 32; ++k) {
        const unsigned short* vrow = V + ((size_t)(r * 32 + k)) * C_ + h * DH_;
        float a = attn[k];
        a0 += a * b2f(vrow[t]);
        a1 += a * b2f(vrow[t + 64]);
    }
    O[qb + t]      = f2b(a0);
    O[qb + t + 64] = f2b(a1);
}

// ---------- LayerNorm: 4 rows/block (1 wave each) ----------
__global__ __launch_bounds__(256)
void ln_kernel(const unsigned short* __restrict__ A, const unsigned short* __restrict__ Res,
               const unsigned short* __restrict__ gamma, const unsigned short* __restrict__ beta,
               unsigned short* __restrict__ out, const int* __restrict__ lens, int use_mask) {
    const int m = blockIdx.x * 4 + (threadIdx.x >> 6);
    const int lane = threadIdx.x & 63;
    const bool masked = use_mask && ((m & 31) >= lens[m >> 5]);
    const size_t base = (size_t)m * C_ + lane * 8;
    float xa[8], xr[8], x[8];
    unpack8(*(const uint4*)(A + base), xa);
    unpack8(*(const uint4*)(Res + base), xr);
    float s = 0.f, ss = 0.f;
#pragma unroll
    for (int e = 0; e < 8; ++e) {
        x[e] = (masked ? 0.f : xa[e]) + xr[e];
        s += x[e]; ss += x[e] * x[e];
    }
#pragma unroll
    for (int off = 32; off > 0; off >>= 1) {
        s  += __shfl_down(s, off);
        ss += __shfl_down(ss, off);
    }
    s = __shfl(s, 0); ss = __shfl(ss, 0);
    const float mu = s * (1.f / 512.f);
    const float rinv = rsqrtf(fmaxf(ss * (1.f / 512.f) - mu * mu, 0.f) + 1e-5f);
    float gg[8], bb[8], y[8];
    unpack8(*(const uint4*)(gamma + lane * 8), gg);
    unpack8(*(const uint4*)(beta + lane * 8), bb);
#pragma unroll
    for (int e = 0; e < 8; ++e) y[e] = (x[e] - mu) * rinv * gg[e] + bb[e];
    *(uint4*)(out + base) = pack8(y);
}

extern "C" void kernel_launch(void* const* d_in, const int* in_sizes, int n_in,
                              void* d_out, int out_size, void* d_ws, size_t ws_size,
                              hipStream_t stream) {
    (void)in_sizes; (void)n_in;
    const void* gene = d_in[0];
    const int*  gidx = (const int*)d_in[1];
    const int*  lens = (const int*)d_in[2];

    int* flag = (int*)d_ws;
    unsigned short* ws0 = (unsigned short*)d_ws + 64;

    size_t off = 0;
    auto take = [&](size_t elems) { unsigned short* p = ws0 + off; off += elems; return p; };
    const size_t WG = (size_t)4 * C_ * C_;
    unsigned short* wQ = take(WG);
    unsigned short* wK = take(WG);
    unsigned short* wV = take(WG);
    unsigned short* wO = take(WG);
    unsigned short* wF = take(WG);
    unsigned short* wP = take((size_t)C_ * C_);
    unsigned short* cbq = take(4 * C_);
    unsigned short* cbk = take(4 * C_);
    unsigned short* cbv = take(4 * C_);
    unsigned short* cbo = take(4 * C_);
    unsigned short* cff = take(4 * C_);
    unsigned short* cg1 = take(4 * C_);
    unsigned short* cb1 = take(4 * C_);
    unsigned short* cg2 = take(4 * C_);
    unsigned short* cb2 = take(4 * C_);
    unsigned short* cpb = take(C_);
    unsigned short* csd = take(C_);
    const size_t wbytes = 128 + off * 2;

    int Rc = 0;
    const int cands[6] = {4096, 2048, 1024, 512, 256, 128};
    for (int i = 0; i < 6; ++i) {
        size_t need = wbytes + (size_t)cands[i] * 135168;
        if (need <= ws_size) { Rc = cands[i]; break; }
    }
    if (Rc == 0) {
        diag_kernel<<<(out_size + 255) / 256, 256, 0, stream>>>(
            (unsigned short*)d_out, out_size, 1000.0f + (float)(ws_size >> 20));
        return;
    }
    const int Mc = Rc * 32;

    unsigned short* X  = take((size_t)Mc * C_);
    unsigned short* A1 = take((size_t)Mc * C_);
    unsigned short* A2 = take((size_t)Mc * C_);
    unsigned short* A3 = take((size_t)Mc * C_);
    unsigned short* S0 = take((size_t)Rc * C_);
    unsigned short* S1 = take((size_t)Rc * C_);
    unsigned short* S2 = take((size_t)Rc * C_);
    unsigned short* S3 = take((size_t)Rc * C_);

    detect_kernel<<<1, 256, 0, stream>>>((const unsigned short*)gene, flag);
    auto cvt = [&](const void* in, unsigned short* out_, int n) {
        cvt_any_kernel<<<(n + 2047) / 2048, 256, 0, stream>>>(in, out_, n, flag);
    };
    cvt(d_in[3], wQ, (int)WG); cvt(d_in[4], wK, (int)WG); cvt(d_in[5], wV, (int)WG);
    cvt(d_in[6], wO, (int)WG); cvt(d_in[7], wF, (int)WG);
    cvt(d_in[17], wP, C_ * C_);
    cvt(d_in[8], cbq, 4 * C_);  cvt(d_in[9], cbk, 4 * C_);  cvt(d_in[10], cbv, 4 * C_);
    cvt(d_in[11], cbo, 4 * C_); cvt(d_in[12], cff, 4 * C_);
    cvt(d_in[13], cg1, 4 * C_); cvt(d_in[14], cb1, 4 * C_);
    cvt(d_in[15], cg2, 4 * C_); cvt(d_in[16], cb2, 4 * C_);
    cvt(d_in[18], cpb, C_);     cvt(d_in[19], csd, C_);

    auto gemm = [&](const unsigned short* Ain, const unsigned short* Win,
                    const unsigned short* bias, unsigned short* Outp, int Mrows, int relu) {
        dim3 grid(Mrows / 128, C_ / 256);
        gemm_bt_kernel<<<grid, 256, 0, stream>>>(Ain, Win, bias, Outp, relu);
    };

    const size_t CC = (size_t)C_ * C_;
    for (int c = 0; c < R_ / Rc; ++c) {
        const int r0 = c * Rc;
        const int* lc = lens + r0;

        gather_kernel<<<Mc * 64 / 256, 256, 0, stream>>>(gene, gidx + (size_t)r0 * L_, lc, X, flag);

        for (int i = 0; i < 2; ++i) {
            const size_t wo_ = (size_t)i * CC;
            gemm(X, wQ + wo_, cbq + i * C_, A1, Mc, 0);
            gemm(X, wK + wo_, cbk + i * C_, A2, Mc, 0);
            gemm(X, wV + wo_, cbv + i * C_, A3, Mc, 0);
            attn_enc_kernel<<<dim3(Rc, H_), 128, 0, stream>>>(A1, A2, A3, A1, lc);
            gemm(A1, wO + wo_, cbo + i * C_, A2, Mc, 0);
            ln_kernel<<<Mc / 4, 256, 0, stream>>>(A2, X, cg1 + i * C_, cb1 + i * C_, X, lc, 1);
            gemm(X, wF + wo_, cff + i * C_, A3, Mc, 1);
            ln_kernel<<<Mc / 4, 256, 0, stream>>>(A3, X, cg2 + i * C_, cb2 + i * C_, X, lc, 0);
        }

        gemm(X, wP, cpb, A1, Mc, 1);
        seed_kernel<<<Rc * 64 / 256, 256, 0, stream>>>(csd, S0);

        {
            const size_t wo_ = (size_t)2 * CC;
            gemm(S0, wQ + wo_, cbq + 2 * C_, S1, Rc, 0);
            gemm(A1, wK + wo_, cbk + 2 * C_, A2, Mc, 0);
            gemm(A1, wV + wo_, cbv + 2 * C_, A3, Mc, 0);
            attn_pma_kernel<<<dim3(Rc, H_), 64, 0, stream>>>(S1, A2, A3, S2, lc);
            gemm(S2, wO + wo_, cbo + 2 * C_, S3, Rc, 0);
            ln_kernel<<<Rc / 4, 256, 0, stream>>>(S3, S0, cg1 + 2 * C_, cb1 + 2 * C_, S0, lc, 0);
            gemm(S0, wF + wo_, cff + 2 * C_, S1, Rc, 1);
            ln_kernel<<<Rc / 4, 256, 0, stream>>>(S1, S0, cg2 + 2 * C_, cb2 + 2 * C_, S0, lc, 0);
        }

        {
            const size_t wo_ = (size_t)3 * CC;
            gemm(S0, wV + wo_, cbv + 3 * C_, S1, Rc, 0);
            gemm(S1, wO + wo_, cbo + 3 * C_, S2, Rc, 0);
            ln_kernel<<<Rc / 4, 256, 0, stream>>>(S2, S0, cg1 + 3 * C_, cb1 + 3 * C_, S0, lc, 0);
            gemm(S0, wF + wo_, cff + 3 * C_, S1, Rc, 1);
            ln_kernel<<<Rc / 4, 256, 0, stream>>>(S1, S0, cg2 + 3 * C_, cb2 + 3 * C_, S0, lc, 0);
        }

        final_kernel<<<Rc * 64 / 256, 256, 0, stream>>>(S0, lc, d_out, flag, (size_t)r0 * C_);
    }
}